// Round 2
// baseline (297.676 us; speedup 1.0000x reference)
//
#include <hip/hip_runtime.h>
#include <hip/hip_bf16.h>

#define N_PTS 131072
#define RES_A 128
#define RES_B 256

typedef __attribute__((ext_vector_type(8))) short short8;
typedef __attribute__((ext_vector_type(4))) float f32x4;

// Transposed grids: gt[axis][i][d*8+c] (row of 128 floats per sample index i).
__device__ __align__(16) float g_gta[3 * RES_A * 128];
__device__ __align__(16) float g_gtb[3 * RES_B * 128];
// bf16 core, padded to 16 rows: g_cbf[scale][x(0..15)][yz(0..63)], x>=8 -> 0.
__device__ __align__(16) short g_cbf[2 * 1024];

__device__ __forceinline__ short bfbits(float x) {
  __hip_bfloat16 h = __float2bfloat16(x);
  return *reinterpret_cast<short*>(&h);
}

// Coalesced-read prep: transpose the 6 grids + bf16-convert the 2 cores.
__global__ __launch_bounds__(256) void prep_kernel(
    const float* __restrict__ g0a, const float* __restrict__ g1a,
    const float* __restrict__ g2a, const float* __restrict__ corea,
    const float* __restrict__ g0b, const float* __restrict__ g1b,
    const float* __restrict__ g2b, const float* __restrict__ coreb) {
  int t = blockIdx.x * 256 + threadIdx.x;
  if (t < 3 * RES_A * 128) {                       // 49152: scale-a grids
    int axis = t / (RES_A * 128);
    int rem = t - axis * (RES_A * 128);
    int i = rem & (RES_A - 1);                     // src index (fastest) -> coalesced read
    int dc = rem >> 7;
    const float* src = axis == 0 ? g0a : (axis == 1 ? g1a : g2a);
    g_gta[axis * (RES_A * 128) + i * 128 + dc] = src[rem];
  } else if (t < 3 * RES_A * 128 + 3 * RES_B * 128) {   // 98304: scale-b grids
    int u = t - 3 * RES_A * 128;
    int axis = u / (RES_B * 128);
    int rem = u - axis * (RES_B * 128);
    int i = rem & (RES_B - 1);
    int dc = rem >> 8;
    const float* src = axis == 0 ? g0b : (axis == 1 ? g1b : g2b);
    g_gtb[axis * (RES_B * 128) + i * 128 + dc] = src[rem];
  } else if (t < 3 * RES_A * 128 + 3 * RES_B * 128 + 2048) {  // 2048: cores
    int e = t - (3 * RES_A * 128 + 3 * RES_B * 128);
    int scale = e >> 10, idx = e & 1023;
    int x = idx >> 6, yz = idx & 63;
    const float* C = scale ? coreb : corea;
    float v = (x < 8) ? C[x * 64 + yz] : 0.0f;
    g_cbf[e] = bfbits(v);
  }
}

// One wave per (point, scale). Columns (lane&15) = output dim d.
// U[x,d] = sum_yz C[x,yz] * (ay[d,y]*az[d,z]) via 2x mfma_f32_16x16x32_bf16,
// then out[n,d] = sum_x ax[d,x] * U[x,d] (4 FMA + cross-group shfl reduce).
__global__ __launch_bounds__(256) void tucker_mfma(
    const float* __restrict__ pts, float* __restrict__ out) {
  const int t = threadIdx.x & 63;
  const int gw = blockIdx.x * 4 + (threadIdx.x >> 6);
  const int scale = gw & 1;
  const int n = gw >> 1;
  const int c = t & 15;   // column: output dim d
  const int g = t >> 4;   // lane group 0..3 (k-slice / x-slice owner)

  const float* __restrict__ gt = scale ? g_gtb : g_gta;
  const short* __restrict__ cb = g_cbf + scale * 1024;
  const int r = scale ? RES_B : RES_A;
  const int astride = r * 128;
  const float half_rm1 = 0.5f * (float)(r - 1);

  const float px = pts[n * 3 + 0];
  const float py = pts[n * 3 + 1];
  const float pz = pts[n * 3 + 2];

  int i0[3], i1[3];
  float w[3];
  const float co[3] = {px, py, pz};
#pragma unroll
  for (int a = 0; a < 3; ++a) {
    float pos = (co[a] + 1.0f) * half_rm1;
    pos = fminf(fmaxf(pos, 0.0f), (float)(r - 1));
    int ii = (int)pos;                 // floor (pos >= 0)
    i0[a] = ii;
    i1[a] = min(ii + 1, r - 1);
    w[a] = pos - (float)ii;
  }

  // az[0..7] for d=c (axis 2)
  float az[8];
  {
    const float* r0 = gt + 2 * astride + i0[2] * 128 + c * 8;
    const float* r1 = gt + 2 * astride + i1[2] * 128 + c * 8;
    f32x4 a0 = *(const f32x4*)r0;
    f32x4 a1 = *(const f32x4*)(r0 + 4);
    f32x4 b0 = *(const f32x4*)r1;
    f32x4 b1 = *(const f32x4*)(r1 + 4);
#pragma unroll
    for (int j = 0; j < 4; ++j) {
      az[j]     = fmaf(w[2], b0[j] - a0[j], a0[j]);
      az[4 + j] = fmaf(w[2], b1[j] - a1[j], a1[j]);
    }
  }

  // ay at y=g and y=g+4 for d=c (axis 1)
  float ayg, ayg4;
  {
    const float* r0 = gt + astride + i0[1] * 128 + c * 8;
    const float* r1 = gt + astride + i1[1] * 128 + c * 8;
    float a0 = r0[g], a4 = r0[g + 4];
    float b0 = r1[g], b4 = r1[g + 4];
    ayg  = fmaf(w[1], b0 - a0, a0);
    ayg4 = fmaf(w[1], b4 - a4, a4);
  }

  // ax at x=4g..4g+3 for d=c (axis 0)
  float ax[4];
  {
    const float* r0 = gt + i0[0] * 128 + c * 8 + 4 * g;
    const float* r1 = gt + i1[0] * 128 + c * 8 + 4 * g;
    f32x4 a0 = *(const f32x4*)r0;
    f32x4 b0 = *(const f32x4*)r1;
#pragma unroll
    for (int j = 0; j < 4; ++j) ax[j] = fmaf(w[0], b0[j] - a0[j], a0[j]);
  }

  // B fragments: lane holds W[k=g*8+j][col=c]; k=yz, first MFMA yz=0..31 (y=g),
  // second yz=32..63 (y=g+4): W = ay[y]*az[z].
  short8 bf0, bf1;
#pragma unroll
  for (int j = 0; j < 8; ++j) {
    bf0[j] = bfbits(ayg * az[j]);
    bf1[j] = bfbits(ayg4 * az[j]);
  }

  // A fragments: lane holds C[x=c][yz=g*8+j] (+32 for second half).
  short8 af0 = *(const short8*)(cb + c * 64 + g * 8);
  short8 af1 = *(const short8*)(cb + c * 64 + 32 + g * 8);

  f32x4 acc = {0.0f, 0.0f, 0.0f, 0.0f};
  acc = __builtin_amdgcn_mfma_f32_16x16x32_bf16(af0, bf0, acc, 0, 0, 0);
  acc = __builtin_amdgcn_mfma_f32_16x16x32_bf16(af1, bf1, acc, 0, 0, 0);

  // acc reg j = U[x=4g+j][d=c]; dot with ax, reduce across the 4 groups.
  float partial = acc[0] * ax[0];
  partial = fmaf(acc[1], ax[1], partial);
  partial = fmaf(acc[2], ax[2], partial);
  partial = fmaf(acc[3], ax[3], partial);
  partial += __shfl_xor(partial, 16);
  partial += __shfl_xor(partial, 32);

  if (t < 16) out[n * 32 + scale * 16 + c] = partial;
}

extern "C" void kernel_launch(void* const* d_in, const int* in_sizes, int n_in,
                              void* d_out, int out_size, void* d_ws, size_t ws_size,
                              hipStream_t stream) {
  const float* pts   = (const float*)d_in[0];
  const float* g0a   = (const float*)d_in[1];
  const float* g1a   = (const float*)d_in[2];
  const float* g2a   = (const float*)d_in[3];
  const float* corea = (const float*)d_in[4];
  const float* g0b   = (const float*)d_in[5];
  const float* g1b   = (const float*)d_in[6];
  const float* g2b   = (const float*)d_in[7];
  const float* coreb = (const float*)d_in[8];
  float* out = (float*)d_out;

  // 49152 + 98304 + 2048 = 149504 elements -> 584 blocks of 256.
  prep_kernel<<<584, 256, 0, stream>>>(g0a, g1a, g2a, corea, g0b, g1b, g2b, coreb);

  // One wave per (point, scale): 131072*2 waves / 4 waves per block.
  tucker_mfma<<<N_PTS * 2 / 4, 256, 0, stream>>>(pts, out);
}

// Round 3
// 245.032 us; speedup vs baseline: 1.2148x; 1.2148x over previous
//
#include <hip/hip_runtime.h>
#include <hip/hip_bf16.h>

#define N_PTS 131072
#define RES_A 128
#define RES_B 256

typedef __attribute__((ext_vector_type(8))) short short8;
typedef __attribute__((ext_vector_type(4))) float f32x4;

// Transposed grids: gt[axis][i][d*8+c] (row of 128 floats per sample index i).
__device__ __align__(16) float g_gta[3 * RES_A * 128];
__device__ __align__(16) float g_gtb[3 * RES_B * 128];
// bf16 core, padded to 16 rows: g_cbf[scale][x(0..15)][yz(0..63)], x>=8 -> 0.
__device__ __align__(16) short g_cbf[2 * 1024];

__device__ __forceinline__ short bfbits(float x) {
  __hip_bfloat16 h = __float2bfloat16(x);
  return *reinterpret_cast<short*>(&h);
}

// LDS-tiled transpose (coalesced read AND write) + core bf16 conversion.
// Blocks 0..143: 32x32 tiles of the six grids; blocks 144..151: cores.
__global__ __launch_bounds__(256) void prep_kernel(
    const float* __restrict__ g0a, const float* __restrict__ g1a,
    const float* __restrict__ g2a, const float* __restrict__ corea,
    const float* __restrict__ g0b, const float* __restrict__ g1b,
    const float* __restrict__ g2b, const float* __restrict__ coreb) {
  __shared__ float tile[32][33];
  const int bid = blockIdx.x;
  if (bid < 144) {
    int r, axis, tl;
    const float* src;
    float* dst;
    if (bid < 48) {
      r = RES_A; axis = bid / 16; tl = bid % 16;
      src = axis == 0 ? g0a : (axis == 1 ? g1a : g2a);
      dst = g_gta + axis * (RES_A * 128);
    } else {
      const int u = bid - 48;
      r = RES_B; axis = u / 32; tl = u % 32;
      src = axis == 0 ? g0b : (axis == 1 ? g1b : g2b);
      dst = g_gtb + axis * (RES_B * 128);
    }
    const int it = tl >> 2, dct = tl & 3;      // i-tile (4 or 8), dc-tile (4)
    const int i0 = it * 32, dc0 = dct * 32;
    const int tx = threadIdx.x & 31, ty = threadIdx.x >> 5;
#pragma unroll
    for (int k = 0; k < 4; ++k)
      tile[ty + k * 8][tx] = src[(dc0 + ty + k * 8) * r + i0 + tx];
    __syncthreads();
#pragma unroll
    for (int k = 0; k < 4; ++k)
      dst[(i0 + ty + k * 8) * 128 + dc0 + tx] = tile[tx][ty + k * 8];
  } else {
    const int e = (bid - 144) * 256 + threadIdx.x;   // 0..2047
    const int scale = e >> 10, idx = e & 1023;
    const int x = idx >> 6, yz = idx & 63;
    const float* C = scale ? coreb : corea;
    g_cbf[e] = bfbits(x < 8 ? C[x * 64 + yz] : 0.0f);
  }
}

// One wave per (4 points, scale). Per point: cols (lane&15) = output dim d,
// U[x,d] = sum_yz C[x,yz]*(ay[d,y]*az[d,z]) via 2x mfma_f32_16x16x32_bf16,
// out[n,d] = sum_x ax[d,x]*U[x,d] (4 FMA + xor-shfl reduce, all lanes get it).
__global__ __launch_bounds__(256) void tucker_mfma(
    const float* __restrict__ pts, float* __restrict__ out) {
  const int t = threadIdx.x & 63;
  const int wv = __builtin_amdgcn_readfirstlane(threadIdx.x >> 6);
  const int scale = blockIdx.y;
  const int n0 = blockIdx.x * 16 + wv * 4;
  const int c = t & 15;   // column: output dim d
  const int g = t >> 4;   // lane group 0..3

  const float* __restrict__ gt = scale ? g_gtb : g_gta;
  const short* __restrict__ cb = g_cbf + scale * 1024;
  const int r = scale ? RES_B : RES_A;
  const int astride = r * 128;
  const float half_rm1 = 0.5f * (float)(r - 1);

  // Core A-fragments: shared across the wave's 4 points.
  const short8 af0 = *(const short8*)(cb + c * 64 + g * 8);
  const short8 af1 = *(const short8*)(cb + c * 64 + 32 + g * 8);

  float az[4][8], ax[4][4], ay0[4], ay1[4];

  // Phase 1: all loads + lerps for 4 points (independent -> deep VMEM pipe).
#pragma unroll
  for (int p = 0; p < 4; ++p) {
    const int n = n0 + p;                       // wave-uniform -> s_load
    const float co0 = pts[n * 3 + 0];
    const float co1 = pts[n * 3 + 1];
    const float co2 = pts[n * 3 + 2];

    float pos0 = fminf(fmaxf((co0 + 1.0f) * half_rm1, 0.0f), (float)(r - 1));
    float pos1 = fminf(fmaxf((co1 + 1.0f) * half_rm1, 0.0f), (float)(r - 1));
    float pos2 = fminf(fmaxf((co2 + 1.0f) * half_rm1, 0.0f), (float)(r - 1));
    int ix0 = (int)pos0, iy0 = (int)pos1, iz0 = (int)pos2;
    int ix1 = min(ix0 + 1, r - 1), iy1 = min(iy0 + 1, r - 1),
        iz1 = min(iz0 + 1, r - 1);
    float wx = pos0 - (float)ix0, wy = pos1 - (float)iy0,
          wz = pos2 - (float)iz0;

    {  // axis 2: az[0..7] for d=c
      const float* r0 = gt + 2 * astride + iz0 * 128 + c * 8;
      const float* r1 = gt + 2 * astride + iz1 * 128 + c * 8;
      f32x4 a0 = *(const f32x4*)r0;
      f32x4 a1 = *(const f32x4*)(r0 + 4);
      f32x4 b0 = *(const f32x4*)r1;
      f32x4 b1 = *(const f32x4*)(r1 + 4);
#pragma unroll
      for (int j = 0; j < 4; ++j) {
        az[p][j]     = fmaf(wz, b0[j] - a0[j], a0[j]);
        az[p][4 + j] = fmaf(wz, b1[j] - a1[j], a1[j]);
      }
    }
    {  // axis 1: ay at y=g and y=g+4 for d=c
      const float* r0 = gt + astride + iy0 * 128 + c * 8;
      const float* r1 = gt + astride + iy1 * 128 + c * 8;
      float a0 = r0[g], a4 = r0[g + 4];
      float b0 = r1[g], b4 = r1[g + 4];
      ay0[p] = fmaf(wy, b0 - a0, a0);
      ay1[p] = fmaf(wy, b4 - a4, a4);
    }
    {  // axis 0: ax at x=4g..4g+3 for d=c
      const float* r0 = gt + ix0 * 128 + c * 8 + 4 * g;
      const float* r1 = gt + ix1 * 128 + c * 8 + 4 * g;
      f32x4 a0 = *(const f32x4*)r0;
      f32x4 b0 = *(const f32x4*)r1;
#pragma unroll
      for (int j = 0; j < 4; ++j) ax[p][j] = fmaf(wx, b0[j] - a0[j], a0[j]);
    }
  }

  // Phase 2: per point, build B fragments, 2 MFMAs, epilogue dot + reduce.
  float res0, res1, res2, res3;
#pragma unroll
  for (int p = 0; p < 4; ++p) {
    short8 bf0, bf1;
#pragma unroll
    for (int j = 0; j < 8; ++j) {
      bf0[j] = bfbits(ay0[p] * az[p][j]);   // k = g*8+j  (y = g)
      bf1[j] = bfbits(ay1[p] * az[p][j]);   // k = 32+g*8+j (y = g+4)
    }
    f32x4 acc = {0.0f, 0.0f, 0.0f, 0.0f};
    acc = __builtin_amdgcn_mfma_f32_16x16x32_bf16(af0, bf0, acc, 0, 0, 0);
    acc = __builtin_amdgcn_mfma_f32_16x16x32_bf16(af1, bf1, acc, 0, 0, 0);
    float partial = acc[0] * ax[p][0];
    partial = fmaf(acc[1], ax[p][1], partial);
    partial = fmaf(acc[2], ax[p][2], partial);
    partial = fmaf(acc[3], ax[p][3], partial);
    partial += __shfl_xor(partial, 16);
    partial += __shfl_xor(partial, 32);     // every lane now has out[p, c]
    if (p == 0) res0 = partial;
    else if (p == 1) res1 = partial;
    else if (p == 2) res2 = partial;
    else res3 = partial;
  }

  // Lane t stores point p = g, column c: 4 x 64B coalesced chunks per wave.
  const float myres = (g == 0) ? res0 : (g == 1) ? res1 : (g == 2) ? res2 : res3;
  out[(n0 + g) * 32 + scale * 16 + c] = myres;
}

extern "C" void kernel_launch(void* const* d_in, const int* in_sizes, int n_in,
                              void* d_out, int out_size, void* d_ws, size_t ws_size,
                              hipStream_t stream) {
  const float* pts   = (const float*)d_in[0];
  const float* g0a   = (const float*)d_in[1];
  const float* g1a   = (const float*)d_in[2];
  const float* g2a   = (const float*)d_in[3];
  const float* corea = (const float*)d_in[4];
  const float* g0b   = (const float*)d_in[5];
  const float* g1b   = (const float*)d_in[6];
  const float* g2b   = (const float*)d_in[7];
  const float* coreb = (const float*)d_in[8];
  float* out = (float*)d_out;

  prep_kernel<<<152, 256, 0, stream>>>(g0a, g1a, g2a, corea, g0b, g1b, g2b, coreb);

  dim3 grid(N_PTS / 16, 2);   // 4 waves/block, 4 points/wave, y = scale
  tucker_mfma<<<grid, 256, 0, stream>>>(pts, out);
}

// Round 6
// 129.286 us; speedup vs baseline: 2.3025x; 1.8953x over previous
//
#include <hip/hip_runtime.h>
#include <hip/hip_bf16.h>
#include <hip/hip_fp16.h>

#define N_PTS 131072
#define RES_A 128
#define RES_B 256

typedef __attribute__((ext_vector_type(8))) short short8;
typedef __attribute__((ext_vector_type(4))) short short4v;
typedef __attribute__((ext_vector_type(4))) float f32x4;
typedef __attribute__((ext_vector_type(4))) unsigned int u32x4;

// f16 transposed grids: [axis][i][d*8+cc] -> 16B (8 halfs) per (i,d) slice.
__device__ __align__(16) short g_gta[3 * RES_A * 128];
__device__ __align__(16) short g_gtb[3 * RES_B * 128];
// bf16 A-fragments: [scale][half][x(16)][k(32)]; k=g*8+j <-> C[x][y=2g+half][z=j]; x>=8 -> 0.
__device__ __align__(16) short g_cbf[2 * 1024];

__device__ __forceinline__ short bfbits(float x) {
  __hip_bfloat16 h = __float2bfloat16(x);
  return *reinterpret_cast<short*>(&h);
}
__device__ __forceinline__ short hbits(float x) {
  __half h = __float2half(x);
  return *reinterpret_cast<short*>(&h);
}
__device__ __forceinline__ float2 h2f2(int v) {
  __half2 h = *reinterpret_cast<__half2*>(&v);
  return __half22float2(h);
}

// LDS-tiled transpose to f16 + core bf16 fragment build.
__global__ __launch_bounds__(256) void prep_kernel(
    const float* __restrict__ g0a, const float* __restrict__ g1a,
    const float* __restrict__ g2a, const float* __restrict__ corea,
    const float* __restrict__ g0b, const float* __restrict__ g1b,
    const float* __restrict__ g2b, const float* __restrict__ coreb) {
  __shared__ float tile[32][33];
  const int bid = blockIdx.x;
  if (bid < 144) {
    int r, axis, tl;
    const float* src;
    short* dst;
    if (bid < 48) {
      r = RES_A; axis = bid / 16; tl = bid % 16;
      src = axis == 0 ? g0a : (axis == 1 ? g1a : g2a);
      dst = g_gta + axis * (RES_A * 128);
    } else {
      const int u = bid - 48;
      r = RES_B; axis = u / 32; tl = u % 32;
      src = axis == 0 ? g0b : (axis == 1 ? g1b : g2b);
      dst = g_gtb + axis * (RES_B * 128);
    }
    const int it = tl >> 2, dct = tl & 3;
    const int i0 = it * 32, dc0 = dct * 32;
    const int tx = threadIdx.x & 31, ty = threadIdx.x >> 5;
#pragma unroll
    for (int k = 0; k < 4; ++k)
      tile[ty + k * 8][tx] = src[(dc0 + ty + k * 8) * r + i0 + tx];
    __syncthreads();
#pragma unroll
    for (int k = 0; k < 4; ++k)
      dst[(i0 + ty + k * 8) * 128 + dc0 + tx] = hbits(tile[tx][ty + k * 8]);
  } else {
    const int e = (bid - 144) * 256 + threadIdx.x;   // 0..2047
    const int scale = e >> 10, rem = e & 1023;
    const int half = rem >> 9, x = (rem >> 5) & 15, k = rem & 31;
    const int gg = k >> 3, j = k & 7;
    const float* C = scale ? coreb : corea;
    const int y = 2 * gg + half;
    g_cbf[e] = bfbits(x < 8 ? C[x * 64 + y * 8 + j] : 0.0f);
  }
}

// One wave per (4 points, scale). Lane t fetches the 16B grid slice for point
// t>>4, dim t&15 (6 independent dwordx4 loads), stages to LDS, __syncthreads
// (real memory barrier - the wave-lockstep assumption without it produced NaN
// in R4/R5), then per point: ds_read fragments, f32 lerp, bf16 products,
// 2x mfma_16x16x32_bf16, dot + shfl reduce.
__global__ __launch_bounds__(256) void tucker_mfma(
    const float* __restrict__ pts, float* __restrict__ out) {
  __shared__ short lds[4][3072];       // 6 buffers x 1KB per wave
  const int t = threadIdx.x & 63;
  const int wv = __builtin_amdgcn_readfirstlane(threadIdx.x >> 6);
  const int scale = blockIdx.y;
  const int n0 = blockIdx.x * 16 + wv * 4;
  const int c = t & 15, g = t >> 4;

  const short* __restrict__ gt = scale ? g_gtb : g_gta;
  const short* __restrict__ cb = g_cbf + scale * 1024;
  const int r = scale ? RES_B : RES_A;
  const float half_rm1 = 0.5f * (float)(r - 1);
  short* lb = &lds[wv][0];

  // Core A-fragments (shared by all 4 points).
  const short8 af0 = *(const short8*)(cb + c * 32 + g * 8);
  const short8 af1 = *(const short8*)(cb + 512 + c * 32 + g * 8);

  // Wave-uniform coords for the 4 points.
  const float* pp = pts + n0 * 3;
  float q[12];
#pragma unroll
  for (int k2 = 0; k2 < 12; ++k2) q[k2] = pp[k2];

  float wx[4], wy[4], wz[4];
  int ix0[4], ix1[4], iy0[4], iy1[4], iz0[4], iz1[4];
#pragma unroll
  for (int p = 0; p < 4; ++p) {
#pragma unroll
    for (int a = 0; a < 3; ++a) {
      float pos = fminf(fmaxf((q[p * 3 + a] + 1.0f) * half_rm1, 0.0f),
                        (float)(r - 1));
      int i0 = (int)pos;
      int i1 = min(i0 + 1, r - 1);
      float w = pos - (float)i0;
      if (a == 0)      { ix0[p] = i0; ix1[p] = i1; wx[p] = w; }
      else if (a == 1) { iy0[p] = i0; iy1[p] = i1; wy[p] = w; }
      else             { iz0[p] = i0; iz1[p] = i1; wz[p] = w; }
    }
  }

  // Per-lane point selection (p = g).
  const int miz0 = g==0?iz0[0]:g==1?iz0[1]:g==2?iz0[2]:iz0[3];
  const int miz1 = g==0?iz1[0]:g==1?iz1[1]:g==2?iz1[2]:iz1[3];
  const int miy0 = g==0?iy0[0]:g==1?iy0[1]:g==2?iy0[2]:iy0[3];
  const int miy1 = g==0?iy1[0]:g==1?iy1[1]:g==2?iy1[2]:iy1[3];
  const int mix0 = g==0?ix0[0]:g==1?ix0[1]:g==2?ix0[2]:ix0[3];
  const int mix1 = g==0?ix1[0]:g==1?ix1[1]:g==2?ix1[2]:ix1[3];

  const short* bx = gt;                  // axis 0
  const short* by = gt + r * 128;        // axis 1
  const short* bz = gt + 2 * r * 128;    // axis 2

  // Issue all 6 gathers back-to-back (no sinking across the fence).
  const u32x4 vz0 = *(const u32x4*)(bz + miz0 * 128 + c * 8);
  const u32x4 vz1 = *(const u32x4*)(bz + miz1 * 128 + c * 8);
  const u32x4 vy0 = *(const u32x4*)(by + miy0 * 128 + c * 8);
  const u32x4 vy1 = *(const u32x4*)(by + miy1 * 128 + c * 8);
  const u32x4 vx0 = *(const u32x4*)(bx + mix0 * 128 + c * 8);
  const u32x4 vx1 = *(const u32x4*)(bx + mix1 * 128 + c * 8);
  __builtin_amdgcn_sched_barrier(0);

  // Stage to LDS: lane t's slice at byte t*16 of each 1KB buffer.
  *(u32x4*)(lb +    0 + t * 8) = vz0;
  *(u32x4*)(lb +  512 + t * 8) = vz1;
  *(u32x4*)(lb + 1024 + t * 8) = vy0;
  *(u32x4*)(lb + 1536 + t * 8) = vy1;
  *(u32x4*)(lb + 2048 + t * 8) = vx0;
  *(u32x4*)(lb + 2560 + t * 8) = vx1;

  __syncthreads();   // real barrier: lgkmcnt(0)+vmcnt(0)+s_barrier

  float res0, res1, res2, res3;
  const int gx = g & 1;   // x-quad index: g>=2 lanes duplicate g-2 (acc==0 there)
#pragma unroll
  for (int p = 0; p < 4; ++p) {
    const int ch = p * 16 + c;
    short8 za = *(const short8*)(lb + ch * 8);
    short8 zb = *(const short8*)(lb + 512 + ch * 8);
    int ya = ((const int*)(lb + 1024))[ch * 4 + g];
    int yb = ((const int*)(lb + 1536))[ch * 4 + g];
    short4v xa = ((const short4v*)(lb + 2048))[ch * 2 + gx];
    short4v xb = ((const short4v*)(lb + 2560))[ch * 2 + gx];

    const float wzp = wz[p], wyp = wy[p], wxp = wx[p];

    float azf[8];
    const int* zai = (const int*)&za;
    const int* zbi = (const int*)&zb;
#pragma unroll
    for (int jj = 0; jj < 4; ++jj) {
      float2 a2 = h2f2(zai[jj]);
      float2 b2 = h2f2(zbi[jj]);
      azf[2 * jj]     = fmaf(wzp, b2.x - a2.x, a2.x);
      azf[2 * jj + 1] = fmaf(wzp, b2.y - a2.y, a2.y);
    }
    float2 ya2 = h2f2(ya);
    float2 yb2 = h2f2(yb);
    float aye = fmaf(wyp, yb2.x - ya2.x, ya2.x);   // ay[2g]
    float ayo = fmaf(wyp, yb2.y - ya2.y, ya2.y);   // ay[2g+1]

    float axf[4];
    const int* xai = (const int*)&xa;
    const int* xbi = (const int*)&xb;
#pragma unroll
    for (int jj = 0; jj < 2; ++jj) {
      float2 a2 = h2f2(xai[jj]);
      float2 b2 = h2f2(xbi[jj]);
      axf[2 * jj]     = fmaf(wxp, b2.x - a2.x, a2.x);
      axf[2 * jj + 1] = fmaf(wxp, b2.y - a2.y, a2.y);
    }

    short8 bf0, bf1;
#pragma unroll
    for (int j = 0; j < 8; ++j) {
      bf0[j] = bfbits(aye * azf[j]);   // k=g*8+j <-> (y=2g,   z=j)
      bf1[j] = bfbits(ayo * azf[j]);   //            (y=2g+1, z=j)
    }
    f32x4 acc = {0.0f, 0.0f, 0.0f, 0.0f};
    acc = __builtin_amdgcn_mfma_f32_16x16x32_bf16(af0, bf0, acc, 0, 0, 0);
    acc = __builtin_amdgcn_mfma_f32_16x16x32_bf16(af1, bf1, acc, 0, 0, 0);

    float partial = acc[0] * axf[0];
    partial = fmaf(acc[1], axf[1], partial);
    partial = fmaf(acc[2], axf[2], partial);
    partial = fmaf(acc[3], axf[3], partial);
    partial += __shfl_xor(partial, 16);
    partial += __shfl_xor(partial, 32);
    if (p == 0) res0 = partial;
    else if (p == 1) res1 = partial;
    else if (p == 2) res2 = partial;
    else res3 = partial;
  }

  const float myres = (g == 0) ? res0 : (g == 1) ? res1 : (g == 2) ? res2 : res3;
  out[(n0 + g) * 32 + scale * 16 + c] = myres;
}

extern "C" void kernel_launch(void* const* d_in, const int* in_sizes, int n_in,
                              void* d_out, int out_size, void* d_ws, size_t ws_size,
                              hipStream_t stream) {
  const float* pts   = (const float*)d_in[0];
  const float* g0a   = (const float*)d_in[1];
  const float* g1a   = (const float*)d_in[2];
  const float* g2a   = (const float*)d_in[3];
  const float* corea = (const float*)d_in[4];
  const float* g0b   = (const float*)d_in[5];
  const float* g1b   = (const float*)d_in[6];
  const float* g2b   = (const float*)d_in[7];
  const float* coreb = (const float*)d_in[8];
  float* out = (float*)d_out;

  prep_kernel<<<152, 256, 0, stream>>>(g0a, g1a, g2a, corea, g0b, g1b, g2b, coreb);

  dim3 grid(N_PTS / 16, 2);   // 4 waves/block, 4 points/wave, y = scale
  tucker_mfma<<<grid, 256, 0, stream>>>(pts, out);
}

// Round 7
// 111.047 us; speedup vs baseline: 2.6806x; 1.1642x over previous
//
#include <hip/hip_runtime.h>
#include <hip/hip_bf16.h>
#include <hip/hip_fp16.h>

#define N_PTS 131072
#define RES_A 128
#define RES_B 256

typedef __attribute__((ext_vector_type(8))) short short8;
typedef __attribute__((ext_vector_type(4))) short short4v;
typedef __attribute__((ext_vector_type(4))) float f32x4;
typedef __attribute__((ext_vector_type(4))) unsigned int u32x4;
typedef __attribute__((ext_vector_type(8))) _Float16 half8;

// f16 transposed grids: [axis][i][d*8+cc] -> 16B (8 halfs) per (i,d) slice.
__device__ __align__(16) short g_gta[3 * RES_A * 128];
__device__ __align__(16) short g_gtb[3 * RES_B * 128];
// f16 A-fragments: [scale][half][x(16)][k(32)]; k=g*8+j <-> C[x][y=2g+half][z=j]; x>=8 -> 0.
__device__ __align__(16) short g_cbf[2 * 1024];

__device__ __forceinline__ short hbits(float x) {
  __half h = __float2half(x);
  return *reinterpret_cast<short*>(&h);
}

// LDS-tiled transpose to f16 + core f16 fragment build.
__global__ __launch_bounds__(256) void prep_kernel(
    const float* __restrict__ g0a, const float* __restrict__ g1a,
    const float* __restrict__ g2a, const float* __restrict__ corea,
    const float* __restrict__ g0b, const float* __restrict__ g1b,
    const float* __restrict__ g2b, const float* __restrict__ coreb) {
  __shared__ float tile[32][33];
  const int bid = blockIdx.x;
  if (bid < 144) {
    int r, axis, tl;
    const float* src;
    short* dst;
    if (bid < 48) {
      r = RES_A; axis = bid / 16; tl = bid % 16;
      src = axis == 0 ? g0a : (axis == 1 ? g1a : g2a);
      dst = g_gta + axis * (RES_A * 128);
    } else {
      const int u = bid - 48;
      r = RES_B; axis = u / 32; tl = u % 32;
      src = axis == 0 ? g0b : (axis == 1 ? g1b : g2b);
      dst = g_gtb + axis * (RES_B * 128);
    }
    const int it = tl >> 2, dct = tl & 3;
    const int i0 = it * 32, dc0 = dct * 32;
    const int tx = threadIdx.x & 31, ty = threadIdx.x >> 5;
#pragma unroll
    for (int k = 0; k < 4; ++k)
      tile[ty + k * 8][tx] = src[(dc0 + ty + k * 8) * r + i0 + tx];
    __syncthreads();
#pragma unroll
    for (int k = 0; k < 4; ++k)
      dst[(i0 + ty + k * 8) * 128 + dc0 + tx] = hbits(tile[tx][ty + k * 8]);
  } else {
    const int e = (bid - 144) * 256 + threadIdx.x;   // 0..2047
    const int scale = e >> 10, rem = e & 1023;
    const int half = rem >> 9, x = (rem >> 5) & 15, k = rem & 31;
    const int gg = k >> 3, j = k & 7;
    const float* C = scale ? coreb : corea;
    const int y = 2 * gg + half;
    g_cbf[e] = hbits(x < 8 ? C[x * 64 + y * 8 + j] : 0.0f);
  }
}

// One wave per (4 points, scale). Lane t fetches the 16B grid slice for point
// t>>4, dim t&15 (6 independent dwordx4 loads), stages to LDS, __syncthreads,
// then per point: ds_read fragments, packed-f16 lerp (v_pk_fma_f16), packed
// products (v_pk_mul_f16, no cvt), 2x mfma_f32_16x16x32_f16, dot + shfl reduce.
__global__ __launch_bounds__(256) void tucker_mfma(
    const float* __restrict__ pts, float* __restrict__ out) {
  __shared__ short lds[4][3072];       // 6 buffers x 1KB per wave
  const int t = threadIdx.x & 63;
  const int wv = __builtin_amdgcn_readfirstlane(threadIdx.x >> 6);
  const int scale = blockIdx.y;
  const int n0 = blockIdx.x * 16 + wv * 4;
  const int c = t & 15, g = t >> 4;

  const short* __restrict__ gt = scale ? g_gtb : g_gta;
  const short* __restrict__ cb = g_cbf + scale * 1024;
  const int r = scale ? RES_B : RES_A;
  const float half_rm1 = 0.5f * (float)(r - 1);
  short* lb = &lds[wv][0];

  // Core A-fragments (shared by all 4 points), f16 bits.
  const half8 af0 = __builtin_bit_cast(half8, *(const short8*)(cb + c * 32 + g * 8));
  const half8 af1 = __builtin_bit_cast(half8, *(const short8*)(cb + 512 + c * 32 + g * 8));

  // Wave-uniform coords for the 4 points.
  const float* pp = pts + n0 * 3;
  float q[12];
#pragma unroll
  for (int k2 = 0; k2 < 12; ++k2) q[k2] = pp[k2];

  float wx[4], wy[4], wz[4];
  int ix0[4], ix1[4], iy0[4], iy1[4], iz0[4], iz1[4];
#pragma unroll
  for (int p = 0; p < 4; ++p) {
#pragma unroll
    for (int a = 0; a < 3; ++a) {
      float pos = fminf(fmaxf((q[p * 3 + a] + 1.0f) * half_rm1, 0.0f),
                        (float)(r - 1));
      int i0 = (int)pos;
      int i1 = min(i0 + 1, r - 1);
      float w = pos - (float)i0;
      if (a == 0)      { ix0[p] = i0; ix1[p] = i1; wx[p] = w; }
      else if (a == 1) { iy0[p] = i0; iy1[p] = i1; wy[p] = w; }
      else             { iz0[p] = i0; iz1[p] = i1; wz[p] = w; }
    }
  }

  // Per-lane point selection (p = g).
  const int miz0 = g==0?iz0[0]:g==1?iz0[1]:g==2?iz0[2]:iz0[3];
  const int miz1 = g==0?iz1[0]:g==1?iz1[1]:g==2?iz1[2]:iz1[3];
  const int miy0 = g==0?iy0[0]:g==1?iy0[1]:g==2?iy0[2]:iy0[3];
  const int miy1 = g==0?iy1[0]:g==1?iy1[1]:g==2?iy1[2]:iy1[3];
  const int mix0 = g==0?ix0[0]:g==1?ix0[1]:g==2?ix0[2]:ix0[3];
  const int mix1 = g==0?ix1[0]:g==1?ix1[1]:g==2?ix1[2]:ix1[3];

  const short* bx = gt;                  // axis 0
  const short* by = gt + r * 128;        // axis 1
  const short* bz = gt + 2 * r * 128;    // axis 2

  // Issue all 6 gathers back-to-back (no sinking across the fence).
  const u32x4 vz0 = *(const u32x4*)(bz + miz0 * 128 + c * 8);
  const u32x4 vz1 = *(const u32x4*)(bz + miz1 * 128 + c * 8);
  const u32x4 vy0 = *(const u32x4*)(by + miy0 * 128 + c * 8);
  const u32x4 vy1 = *(const u32x4*)(by + miy1 * 128 + c * 8);
  const u32x4 vx0 = *(const u32x4*)(bx + mix0 * 128 + c * 8);
  const u32x4 vx1 = *(const u32x4*)(bx + mix1 * 128 + c * 8);
  __builtin_amdgcn_sched_barrier(0);

  // Stage to LDS: lane t's slice at byte t*16 of each 1KB buffer.
  *(u32x4*)(lb +    0 + t * 8) = vz0;
  *(u32x4*)(lb +  512 + t * 8) = vz1;
  *(u32x4*)(lb + 1024 + t * 8) = vy0;
  *(u32x4*)(lb + 1536 + t * 8) = vy1;
  *(u32x4*)(lb + 2048 + t * 8) = vx0;
  *(u32x4*)(lb + 2560 + t * 8) = vx1;

  __syncthreads();   // real barrier: lgkmcnt(0)+vmcnt(0)+s_barrier

  float res0, res1, res2, res3;
  const int gx = g & 1;   // x-quad index: g>=2 lanes duplicate g-2 (acc==0 there)
#pragma unroll
  for (int p = 0; p < 4; ++p) {
    const int ch = p * 16 + c;
    short8 za = *(const short8*)(lb + ch * 8);
    short8 zb = *(const short8*)(lb + 512 + ch * 8);
    int ya = ((const int*)(lb + 1024))[ch * 4 + g];
    int yb = ((const int*)(lb + 1536))[ch * 4 + g];
    short4v xa = ((const short4v*)(lb + 2048))[ch * 2 + gx];
    short4v xb = ((const short4v*)(lb + 2560))[ch * 2 + gx];

    const __half2 wz2 = __float2half2_rn(wz[p]);
    const __half2 wy2 = __float2half2_rn(wy[p]);
    const __half2 wx2 = __float2half2_rn(wx[p]);

    // az lerp: 4x v_pk_sub + 4x v_pk_fma
    const __half2* zah = reinterpret_cast<const __half2*>(&za);
    const __half2* zbh = reinterpret_cast<const __half2*>(&zb);
    __half2 azh0 = __hfma2(wz2, __hsub2(zbh[0], zah[0]), zah[0]);
    __half2 azh1 = __hfma2(wz2, __hsub2(zbh[1], zah[1]), zah[1]);
    __half2 azh2 = __hfma2(wz2, __hsub2(zbh[2], zah[2]), zah[2]);
    __half2 azh3 = __hfma2(wz2, __hsub2(zbh[3], zah[3]), zah[3]);

    // ay lerp (packed pair), then broadcast lo/hi
    const __half2 yah = *reinterpret_cast<const __half2*>(&ya);
    const __half2 ybh = *reinterpret_cast<const __half2*>(&yb);
    const __half2 ayh = __hfma2(wy2, __hsub2(ybh, yah), yah);
    const __half2 aye2 = __low2half2(ayh);    // {ay[2g],  ay[2g]}
    const __half2 ayo2 = __high2half2(ayh);   // {ay[2g+1],ay[2g+1]}

    // B fragments: products stay in f16 (no conversion at all)
    union { __half2 h2[4]; half8 v8; } b0u, b1u;
    b0u.h2[0] = __hmul2(aye2, azh0); b0u.h2[1] = __hmul2(aye2, azh1);
    b0u.h2[2] = __hmul2(aye2, azh2); b0u.h2[3] = __hmul2(aye2, azh3);
    b1u.h2[0] = __hmul2(ayo2, azh0); b1u.h2[1] = __hmul2(ayo2, azh1);
    b1u.h2[2] = __hmul2(ayo2, azh2); b1u.h2[3] = __hmul2(ayo2, azh3);

    // ax lerp in f16, then cvt 4 values to f32 for the epilogue dot
    const __half2* xah = reinterpret_cast<const __half2*>(&xa);
    const __half2* xbh = reinterpret_cast<const __half2*>(&xb);
    __half2 axh0 = __hfma2(wx2, __hsub2(xbh[0], xah[0]), xah[0]);
    __half2 axh1 = __hfma2(wx2, __hsub2(xbh[1], xah[1]), xah[1]);
    float2 ax01 = __half22float2(axh0);
    float2 ax23 = __half22float2(axh1);

    f32x4 acc = {0.0f, 0.0f, 0.0f, 0.0f};
    acc = __builtin_amdgcn_mfma_f32_16x16x32_f16(af0, b0u.v8, acc, 0, 0, 0);
    acc = __builtin_amdgcn_mfma_f32_16x16x32_f16(af1, b1u.v8, acc, 0, 0, 0);

    float partial = acc[0] * ax01.x;
    partial = fmaf(acc[1], ax01.y, partial);
    partial = fmaf(acc[2], ax23.x, partial);
    partial = fmaf(acc[3], ax23.y, partial);
    partial += __shfl_xor(partial, 16);
    partial += __shfl_xor(partial, 32);
    if (p == 0) res0 = partial;
    else if (p == 1) res1 = partial;
    else if (p == 2) res2 = partial;
    else res3 = partial;
  }

  const float myres = (g == 0) ? res0 : (g == 1) ? res1 : (g == 2) ? res2 : res3;
  out[(n0 + g) * 32 + scale * 16 + c] = myres;
}

extern "C" void kernel_launch(void* const* d_in, const int* in_sizes, int n_in,
                              void* d_out, int out_size, void* d_ws, size_t ws_size,
                              hipStream_t stream) {
  const float* pts   = (const float*)d_in[0];
  const float* g0a   = (const float*)d_in[1];
  const float* g1a   = (const float*)d_in[2];
  const float* g2a   = (const float*)d_in[3];
  const float* corea = (const float*)d_in[4];
  const float* g0b   = (const float*)d_in[5];
  const float* g1b   = (const float*)d_in[6];
  const float* g2b   = (const float*)d_in[7];
  const float* coreb = (const float*)d_in[8];
  float* out = (float*)d_out;

  prep_kernel<<<152, 256, 0, stream>>>(g0a, g1a, g2a, corea, g0b, g1b, g2b, coreb);

  dim3 grid(N_PTS / 16, 2);   // 4 waves/block, 4 points/wave, y = scale
  tucker_mfma<<<grid, 256, 0, stream>>>(pts, out);
}